// Round 3
// baseline (1099.035 us; speedup 1.0000x reference)
//
#include <hip/hip_runtime.h>
#include <hip/hip_bf16.h>
#include <cstdint>

#define B_   256
#define L_   196
#define ENC_ 2048
#define DEC_ 512
#define ATT_ 512
#define M_TOT (B_*L_)   // 50176, divisible by 32

typedef short short8 __attribute__((ext_vector_type(8)));
typedef float f32x16 __attribute__((ext_vector_type(16)));

__device__ __forceinline__ unsigned short f2bf(float f) {
    union { float f; unsigned u; } v; v.f = f;
    unsigned u = v.u;
    return (unsigned short)((u + 0x7FFFu + ((u >> 16) & 1u)) >> 16);  // RNE
}

__device__ __forceinline__ unsigned pack2(float2 v) {
    return (unsigned)f2bf(v.x) | ((unsigned)f2bf(v.y) << 16);
}

__device__ __forceinline__ void gl_lds16(const void* g, void* l) {
    __builtin_amdgcn_global_load_lds((const __attribute__((address_space(1))) unsigned int*)g,
                                     (__attribute__((address_space(3))) unsigned int*)l,
                                     16, 0, 0);
}

// ---------- K0a: W_enc [ENC][ATT] fp32 -> WT [ATT][ENC] bf16 (transpose+convert) ----------
__global__ void k_transpose(const float* __restrict__ W, unsigned short* __restrict__ WT) {
    __shared__ float S[32*33];
    const int k0 = blockIdx.x * 32, n0 = blockIdx.y * 32;
    const int t  = threadIdx.x;
    const int c31 = t & 31, q = t >> 5;   // q = 0..7
#pragma unroll
    for (int i = 0; i < 4; ++i) {
        int kl = q + i*8;
        S[c31*33 + kl] = W[(size_t)(k0+kl)*ATT_ + n0 + c31];   // coalesced along n
    }
    __syncthreads();
#pragma unroll
    for (int i = 0; i < 4; ++i) {
        int nn = q + i*8;
        WT[(size_t)(n0+nn)*ENC_ + k0 + c31] = f2bf(S[nn*33 + c31]);  // coalesced along k
    }
}

// ---------- K0b: att2c[b][n] = h[b]@W_dec + b_dec + b_enc ; gate[b] = sigmoid(h@W_beta+b_beta) ----------
// 4 batches per block (grid 64): Wdec stream amortized 4x (256MB -> 64MB of L2/L3 traffic),
// 8 FMAs per 2 global loads in the k-loop.
__global__ void k_prep2(const float* __restrict__ h, const float* __restrict__ Wdec,
                        const float* __restrict__ bdec, const float* __restrict__ benc,
                        const float* __restrict__ Wbeta, const float* __restrict__ bbeta,
                        float* __restrict__ att2c, float* __restrict__ gate) {
    const int b0 = blockIdx.x * 4, t = threadIdx.x;   // 256 threads
    __shared__ float hs[4][DEC_];
    __shared__ float pr[4][4];
#pragma unroll
    for (int i = 0; i < 4; ++i) {
        hs[i][t]       = h[(size_t)(b0+i)*DEC_ + t];
        hs[i][t + 256] = h[(size_t)(b0+i)*DEC_ + t + 256];
    }
    __syncthreads();
    float a0[4] = {0.f,0.f,0.f,0.f}, a1[4] = {0.f,0.f,0.f,0.f};
    for (int k = 0; k < DEC_; ++k) {
        float w0 = Wdec[(size_t)k*ATT_ + t];
        float w1 = Wdec[(size_t)k*ATT_ + t + 256];
#pragma unroll
        for (int i = 0; i < 4; ++i) {
            a0[i] = fmaf(hs[i][k], w0, a0[i]);
            a1[i] = fmaf(hs[i][k], w1, a1[i]);
        }
    }
    const float bd0 = bdec[t] + benc[t], bd1 = bdec[t+256] + benc[t+256];
#pragma unroll
    for (int i = 0; i < 4; ++i) {
        att2c[(size_t)(b0+i)*ATT_ + t]       = a0[i] + bd0;
        att2c[(size_t)(b0+i)*ATT_ + t + 256] = a1[i] + bd1;
    }
    const int wid = t >> 6;
    const float wb0 = Wbeta[t], wb1 = Wbeta[t+256];
#pragma unroll
    for (int i = 0; i < 4; ++i) {
        float p = hs[i][t]*wb0 + hs[i][t+256]*wb1;
#pragma unroll
        for (int mask = 32; mask; mask >>= 1) p += __shfl_xor(p, mask, 64);
        if ((t & 63) == 0) pr[i][wid] = p;
    }
    __syncthreads();
    if (t < 4)
        gate[b0+t] = 1.f / (1.f + __expf(-(pr[t][0]+pr[t][1]+pr[t][2]+pr[t][3] + bbeta[0])));
}

// ---------- K1: att[m] = sum_n relu(x[m]@W_enc[:,n] + att2c[b(m)][n]) * W_full[n] ----------
// OCCUPANCY REDESIGN (round-1 post-mortem: 2 waves/SIMD reg-cap was the latency wall):
//   tile 32(M) x 512(N), BK=16, 4 waves, wave tile 32x128 -> acc[4] = 64 AGPR (was 128),
//   total regs ~120 -> 3-4 waves/SIMD; LDS 35KB (was 73KB) -> 4 blocks/CU by LDS.
//   Grid 1568 blocks (2.04 rounds of 768 -> better tail). x still read exactly once.
// LDS layout (both-sides swizzle, rule #21): 16B chunk of row r, k-half h at byte
//   r*32 + (h ^ ((r>>2)&1))*16. Frag reads (lane31=row, laneh=h) hit all 8 bank-quads
//   uniformly (4 lanes each per half-wave). gl_lds writes LDS-linear; the inverse
//   permutation is applied to the per-lane GLOBAL source offset (bsrc).
// Schedule: plain m97-style 2-phase, one __syncthreads per BK=16 step; compiler handles
//   waitcnts (round-1 A/B: hand-rolled counted vmcnt was neutral-to-worse here).
__global__ __launch_bounds__(256, 3) void k_gemm(
        const float* __restrict__ x, const unsigned short* __restrict__ WT,
        const float* __restrict__ att2c, const float* __restrict__ Wfull,
        float* __restrict__ att) {
    __shared__ alignas(16) unsigned short Ab[2][512];     // 1 KB each: 32 rows x 16 k
    __shared__ alignas(16) unsigned short Bb[2][8192];    // 16 KB each: 512 rows x 16 k
    __shared__ float att_ws[4][32];

    const int tid   = threadIdx.x;
    const int wave  = tid >> 6;
    const int lane  = tid & 63;
    const int lane31 = lane & 31;
    const int laneh  = lane >> 5;
    const int m0 = blockIdx.x * 32;

    f32x16 acc[4];
#pragma unroll
    for (int j = 0; j < 4; ++j)
#pragma unroll
        for (int r = 0; r < 16; ++r) acc[j][r] = 0.f;

    // B staging: 4 gl_lds (1KB each) per wave per iter. LDS chunk slot p=(wave*4+j)*64+lane
    // holds (n = p>>1, h = (p&1) ^ ((n>>2)&1)) -> per-lane global source offset.
    int bsrc[4];
#pragma unroll
    for (int j = 0; j < 4; ++j) {
        int p = (wave*4 + j)*64 + lane;
        int n = p >> 1;
        int hh = (p & 1) ^ ((n >> 2) & 1);
        bsrc[j] = n*ENC_ + hh*8;
    }
    // A staging: thread t -> row am = t>>3, float-pair ae = t&7 (k = 2*ae, 2*ae+1).
    const int am = tid >> 3, ae = tid & 7, ah = ae >> 2;
    const int awoff = am*32 + ((ah ^ ((am >> 2) & 1)) << 4) + (ae & 3)*4;  // byte
    const float* xrow = x + (size_t)(m0 + am)*ENC_ + 2*ae;

    // Fragment-read byte offsets (swizzled).
    const int aoff = lane31*32 + ((laneh ^ ((lane31 >> 2) & 1)) << 4);
    int boffr[4];
#pragma unroll
    for (int ni = 0; ni < 4; ++ni) {
        int n = wave*128 + ni*32 + lane31;
        boffr[ni] = n*32 + ((laneh ^ ((n >> 2) & 1)) << 4);
    }

    // ---- prologue: stage K=0 into buffer 0; preload x(1) ----
#pragma unroll
    for (int j = 0; j < 4; ++j)
        gl_lds16(WT + bsrc[j], (void*)&Bb[0][(wave*4 + j)*512]);
    {
        float2 p0 = *(const float2*)xrow;
        *(unsigned*)((char*)&Ab[0][0] + awoff) = pack2(p0);
    }
    float2 pxA = *(const float2*)(xrow + 16);
    float2 pxB;
    __syncthreads();

#define GITER(K, PXOLD, PXNEW)                                                        \
{                                                                                     \
    const int cur = (K) & 1, nxt = cur ^ 1;                                           \
    if ((K) + 2 < 128)                                                                \
        PXNEW = *(const float2*)(xrow + ((K)+2)*16);                                  \
    if ((K) + 1 < 128) {                                                              \
        _Pragma("unroll") for (int j = 0; j < 4; ++j)                                 \
            gl_lds16(WT + bsrc[j] + ((K)+1)*16, (void*)&Bb[nxt][(wave*4 + j)*512]);   \
    }                                                                                 \
    short8 afr, bfr[4];                                                               \
    afr = *(const short8*)((const char*)&Ab[cur][0] + aoff);                          \
    _Pragma("unroll") for (int ni = 0; ni < 4; ++ni)                                  \
        bfr[ni] = *(const short8*)((const char*)&Bb[cur][0] + boffr[ni]);             \
    _Pragma("unroll") for (int ni = 0; ni < 4; ++ni)                                  \
        acc[ni] = __builtin_amdgcn_mfma_f32_32x32x16_bf16(afr, bfr[ni], acc[ni], 0, 0, 0); \
    if ((K) + 1 < 128)                                                                \
        *(unsigned*)((char*)&Ab[nxt][0] + awoff) = pack2(PXOLD);                      \
    __syncthreads();                                                                  \
}

    for (int KK = 0; KK < 64; ++KK) {
        GITER(2*KK,     pxA, pxB)
        GITER(2*KK + 1, pxB, pxA)
    }
#undef GITER

    // ---- epilogue: relu(acc + att2c[b][n]) * Wfull[n], reduce over n, write att[m] ----
    // Final iter (K=127) read Bb[1] and ended with a barrier -> Bb[0] safe to reuse.
    float* epi = (float*)&Bb[0][0];  // [0..511]=Wfull, [512..1023]=att2c[b0], [1024..1535]=att2c[b1]
    const int b0i = m0 / L_;
    const int b1i = (m0 + 31) / L_;
    epi[tid]        = Wfull[tid];
    epi[256 + tid]  = Wfull[256 + tid];
    epi[512 + tid]  = att2c[(size_t)b0i*ATT_ + tid];
    epi[768 + tid]  = att2c[(size_t)b0i*ATT_ + 256 + tid];
    epi[1024 + tid] = att2c[(size_t)b1i*ATT_ + tid];
    epi[1280 + tid] = att2c[(size_t)b1i*ATT_ + 256 + tid];
    __syncthreads();
    const int split = (b0i + 1) * L_;   // first global row of batch b1
#pragma unroll
    for (int reg = 0; reg < 16; ++reg) {
        int r32 = (reg & 3) + 8*(reg >> 2) + 4*laneh;   // verified C/D map (m74/m101)
        int off = (m0 + r32 >= split) ? 1024 : 512;
        float v = 0.f;
#pragma unroll
        for (int ni = 0; ni < 4; ++ni) {
            int n = wave*128 + ni*32 + lane31;
            float tv = acc[ni][reg] + epi[off + n];
            v = fmaf(fmaxf(tv, 0.f), epi[n], v);
        }
#pragma unroll
        for (int mask = 16; mask; mask >>= 1) v += __shfl_xor(v, mask, 64);
        if (lane31 == 0) att_ws[wave][r32] = v;
    }
    __syncthreads();
    if (tid < 32)
        att[m0 + tid] = att_ws[0][tid] + att_ws[1][tid] + att_ws[2][tid] + att_ws[3][tid];
}

// ---------- K2: softmax over L, z = alpha@x[b], out0 = gate*z, out1 = alpha ----------
// grid (B, 2): each block handles 1024 of 2048 ENC cols -> 512 blocks = 2/CU.
// Reversed block order + 7-deep float4 software pipeline (see round-1 notes).
__global__ __launch_bounds__(256) void k_softz(
        const float* __restrict__ att, const float* __restrict__ x,
        const float* __restrict__ gate, float* __restrict__ out) {
    const int b = (B_ - 1) - (int)blockIdx.x;
    const int s = blockIdx.y, t = threadIdx.x;   // 256 threads
    __shared__ float sa[L_];
    __shared__ float red[8];
    const int wid = t >> 6, lane = t & 63;
    float v = (t < L_) ? att[b*L_ + t] : -1e30f;
    float m = v;
#pragma unroll
    for (int mask = 32; mask; mask >>= 1) m = fmaxf(m, __shfl_xor(m, mask, 64));
    if (lane == 0) red[wid] = m;
    __syncthreads();
    m = fmaxf(fmaxf(red[0], red[1]), fmaxf(red[2], red[3]));
    float e = (t < L_) ? __expf(v - m) : 0.f;
    float sum = e;
#pragma unroll
    for (int mask = 32; mask; mask >>= 1) sum += __shfl_xor(sum, mask, 64);
    if (lane == 0) red[4 + wid] = sum;
    __syncthreads();
    sum = red[4] + red[5] + red[6] + red[7];
    float alpha = e / sum;
    if (t < L_) {
        sa[t] = alpha;
        if (s == 0) out[(size_t)B_*ENC_ + (size_t)b*L_ + t] = alpha;
    }
    __syncthreads();
    const float* xb = x + (size_t)b*L_*ENC_ + s*1024 + t*4;
    float4 z = {0.f, 0.f, 0.f, 0.f};
    float4 u[7], w[7];
#pragma unroll
    for (int i = 0; i < 7; ++i) u[i] = *(const float4*)(xb + (size_t)i*ENC_);
    for (int l0 = 0; l0 < 183; l0 += 7) {          // consumes groups 0..182, prefetches 7..189
#pragma unroll
        for (int i = 0; i < 7; ++i)
            w[i] = *(const float4*)(xb + (size_t)(l0 + 7 + i)*ENC_);
#pragma unroll
        for (int i = 0; i < 7; ++i) {
            float a_ = sa[l0 + i];
            z.x = fmaf(a_, u[i].x, z.x); z.y = fmaf(a_, u[i].y, z.y);
            z.z = fmaf(a_, u[i].z, z.z); z.w = fmaf(a_, u[i].w, z.w);
        }
#pragma unroll
        for (int i = 0; i < 7; ++i) u[i] = w[i];
    }
#pragma unroll
    for (int i = 0; i < 7; ++i) {                  // final group l = 189..195
        float a_ = sa[189 + i];
        z.x = fmaf(a_, u[i].x, z.x); z.y = fmaf(a_, u[i].y, z.y);
        z.z = fmaf(a_, u[i].z, z.z); z.w = fmaf(a_, u[i].w, z.w);
    }
    const float gt = gate[b];
    float4 o; o.x = gt*z.x; o.y = gt*z.y; o.z = gt*z.z; o.w = gt*z.w;
    *(float4*)(out + (size_t)b*ENC_ + s*1024 + t*4) = o;
}

extern "C" void kernel_launch(void* const* d_in, const int* in_sizes, int n_in,
                              void* d_out, int out_size, void* d_ws, size_t ws_size,
                              hipStream_t stream) {
    const float* x      = (const float*)d_in[0];
    const float* h      = (const float*)d_in[1];
    const float* W_enc  = (const float*)d_in[2];
    const float* b_enc  = (const float*)d_in[3];
    const float* W_dec  = (const float*)d_in[4];
    const float* b_dec  = (const float*)d_in[5];
    const float* W_full = (const float*)d_in[6];
    // d_in[7] = b_full: softmax is shift-invariant -> unused
    const float* W_beta = (const float*)d_in[8];
    const float* b_beta = (const float*)d_in[9];
    float* out = (float*)d_out;

    char* ws = (char*)d_ws;
    unsigned short* WT = (unsigned short*)ws;                              // 2 MB
    float* att2c  = (float*)(ws + 2*1024*1024);                            // 512 KB
    float* gate   = (float*)(ws + 2*1024*1024 + 512*1024);                 // 1 KB
    float* attbuf = (float*)(ws + 2*1024*1024 + 512*1024 + 1024);          // 200 KB

    k_transpose<<<dim3(ENC_/32, ATT_/32), 256, 0, stream>>>(W_enc, WT);
    k_prep2   <<<B_/4, 256, 0, stream>>>(h, W_dec, b_dec, b_enc, W_beta, b_beta, att2c, gate);
    k_gemm    <<<M_TOT/32, 256, 0, stream>>>(x, WT, att2c, W_full, attbuf);
    k_softz   <<<dim3(B_, 2), 256, 0, stream>>>(attbuf, x, gate, out);
}

// Round 6
// 808.353 us; speedup vs baseline: 1.3596x; 1.3596x over previous
//
#include <hip/hip_runtime.h>
#include <hip/hip_bf16.h>
#include <cstdint>

#define B_   256
#define L_   196
#define ENC_ 2048
#define DEC_ 512
#define ATT_ 512
#define M_TOT (B_*L_)   // 50176, divisible by 128

typedef short short8 __attribute__((ext_vector_type(8)));
typedef float f32x16 __attribute__((ext_vector_type(16)));

__device__ __forceinline__ unsigned short f2bf(float f) {
    union { float f; unsigned u; } v; v.f = f;
    unsigned u = v.u;
    return (unsigned short)((u + 0x7FFFu + ((u >> 16) & 1u)) >> 16);  // RNE
}

__device__ __forceinline__ void gl_lds16(const void* g, void* l) {
    __builtin_amdgcn_global_load_lds((const __attribute__((address_space(1))) unsigned int*)g,
                                     (__attribute__((address_space(3))) unsigned int*)l,
                                     16, 0, 0);
}

// ---------- K0a: W_enc [ENC][ATT] fp32 -> WT [ATT][ENC] bf16 (transpose+convert) ----------
__global__ void k_transpose(const float* __restrict__ W, unsigned short* __restrict__ WT) {
    __shared__ float S[32*33];
    const int k0 = blockIdx.x * 32, n0 = blockIdx.y * 32;
    const int t  = threadIdx.x;
    const int c31 = t & 31, q = t >> 5;   // q = 0..7
#pragma unroll
    for (int i = 0; i < 4; ++i) {
        int kl = q + i*8;
        S[c31*33 + kl] = W[(size_t)(k0+kl)*ATT_ + n0 + c31];   // coalesced along n
    }
    __syncthreads();
#pragma unroll
    for (int i = 0; i < 4; ++i) {
        int nn = q + i*8;
        WT[(size_t)(n0+nn)*ENC_ + k0 + c31] = f2bf(S[nn*33 + c31]);  // coalesced along k
    }
}

// ---------- K0b: att2c[b][n] = h[b]@W_dec + b_dec + b_enc ; gate[b] = sigmoid(h@W_beta+b_beta) ----------
__global__ void k_prep2(const float* __restrict__ h, const float* __restrict__ Wdec,
                        const float* __restrict__ bdec, const float* __restrict__ benc,
                        const float* __restrict__ Wbeta, const float* __restrict__ bbeta,
                        float* __restrict__ att2c, float* __restrict__ gate) {
    const int b0 = blockIdx.x * 4, t = threadIdx.x;   // 256 threads
    __shared__ float hs[4][DEC_];
    __shared__ float pr[4][4];
#pragma unroll
    for (int i = 0; i < 4; ++i) {
        hs[i][t]       = h[(size_t)(b0+i)*DEC_ + t];
        hs[i][t + 256] = h[(size_t)(b0+i)*DEC_ + t + 256];
    }
    __syncthreads();
    float a0[4] = {0.f,0.f,0.f,0.f}, a1[4] = {0.f,0.f,0.f,0.f};
    for (int k = 0; k < DEC_; ++k) {
        float w0 = Wdec[(size_t)k*ATT_ + t];
        float w1 = Wdec[(size_t)k*ATT_ + t + 256];
#pragma unroll
        for (int i = 0; i < 4; ++i) {
            a0[i] = fmaf(hs[i][k], w0, a0[i]);
            a1[i] = fmaf(hs[i][k], w1, a1[i]);
        }
    }
    const float bd0 = bdec[t] + benc[t], bd1 = bdec[t+256] + benc[t+256];
#pragma unroll
    for (int i = 0; i < 4; ++i) {
        att2c[(size_t)(b0+i)*ATT_ + t]       = a0[i] + bd0;
        att2c[(size_t)(b0+i)*ATT_ + t + 256] = a1[i] + bd1;
    }
    const int wid = t >> 6;
    const float wb0 = Wbeta[t], wb1 = Wbeta[t+256];
#pragma unroll
    for (int i = 0; i < 4; ++i) {
        float p = hs[i][t]*wb0 + hs[i][t+256]*wb1;
#pragma unroll
        for (int mask = 32; mask; mask >>= 1) p += __shfl_xor(p, mask, 64);
        if ((t & 63) == 0) pr[i][wid] = p;
    }
    __syncthreads();
    if (t < 4)
        gate[b0+t] = 1.f / (1.f + __expf(-(pr[t][0]+pr[t][1]+pr[t][2]+pr[t][3] + bbeta[0])));
}

// ---------- K1: att[m] = sum_n relu(x[m]@W_enc[:,n] + att2c[b(m)][n]) * W_full[n] ----------
// DE-RISKED FAT-TILE (rounds 4/5 never ran: container failures; raw-barrier schedule is
// the only untested machinery -> dropped). This variant = round-0's PROVEN control flow
// (one __syncthreads/K-step full-drain, gl_lds B prefetch into nxt, reg-staged A,
// compiler waitcnts) with tile geometry changed per the round-3 cost model:
//   BM=128 x BN=512 (x read once), BK=32, 512 threads = 8 waves (2M x 4N),
//   wave tile 64x128, acc[2][4] = 128 AGPR. Grid 392 blocks. B-DMA bytes and barrier
//   count per output row HALVED vs round-0.
// LDS chunk-swizzle = round-0's PROVEN formula: chunk(r,kc) = r*4 + (kc ^ ((r>>1)&3)),
// 16B chunks (8 distinct bank-quad slots per 8 rows = 4-way, minimum phases; round-4's
// kc^(r&3) was worse: 4 slots = 8-way). gl_lds writes LDS-linear; inverse permutation
// applied to per-lane GLOBAL source (bsrc). A ds_write: one b128 per thread, same swizzle.
__global__ __launch_bounds__(512, 2) void k_gemm(
        const float* __restrict__ x, const unsigned short* __restrict__ WT,
        const float* __restrict__ att2c, const float* __restrict__ Wfull,
        float* __restrict__ att) {
    __shared__ alignas(16) unsigned short Ab[2][128*32];   // 8 KB each
    __shared__ alignas(16) unsigned short Bb[2][512*32];   // 32 KB each
    __shared__ float att_ws[4][128];

    const int tid   = threadIdx.x;
    const int wave  = tid >> 6;
    const int lane  = tid & 63;
    const int lane31 = lane & 31;
    const int laneh  = lane >> 5;
    const int wr = wave >> 2, wc = wave & 3;   // wave grid 2(M) x 4(N)
    const int m0 = blockIdx.x * 128;

    f32x16 acc[2][4];
#pragma unroll
    for (int i = 0; i < 2; ++i)
#pragma unroll
        for (int j = 0; j < 4; ++j)
#pragma unroll
            for (int r = 0; r < 16; ++r) acc[i][j][r] = 0.f;

    // B staging: 4 gl_lds (1KB each) per wave per step. LDS chunk slot p=(wave*4+j)*64+lane
    // holds (row n = p>>2, k-chunk kc = (p&3) ^ ((n>>1)&3)) -> per-lane global source.
    int bsrc[4], bdst[4];
#pragma unroll
    for (int j = 0; j < 4; ++j) {
        int p = (wave*4 + j)*64 + lane;
        int n = p >> 2;
        int kc = (p & 3) ^ ((n >> 1) & 3);
        bsrc[j] = n*ENC_ + kc*8;
        bdst[j] = (wave*4 + j)*512;     // wave-uniform LDS base (elements), lane-linear x16B
    }
    // A staging: thread t -> row ar = t>>2, k-chunk g = t&3; one b128 write per step.
    const int ar = tid >> 2, g = tid & 3;
    const int achunk = ar*4 + (g ^ ((ar >> 1) & 3));
    const float* xrow = x + (size_t)(m0 + ar)*ENC_ + g*8;

    // Fragment-read element offsets (swizzled): kc = ks*2 + laneh.
    int ard[2][2], brd[2][4];
#pragma unroll
    for (int ks = 0; ks < 2; ++ks) {
        const int kc = ks*2 + laneh;
#pragma unroll
        for (int mi = 0; mi < 2; ++mi) {
            int m = wr*64 + mi*32 + lane31;
            ard[ks][mi] = (m*4 + (kc ^ ((m >> 1) & 3)))*8;
        }
#pragma unroll
        for (int ni = 0; ni < 4; ++ni) {
            int n = wc*128 + ni*32 + lane31;
            brd[ks][ni] = (n*4 + (kc ^ ((n >> 1) & 3)))*8;
        }
    }

    // ---- prologue: stage step 0 into buffer 0 ----
#pragma unroll
    for (int j = 0; j < 4; ++j)
        gl_lds16(WT + bsrc[j], (void*)&Bb[0][bdst[j]]);
    float4 pa = *(const float4*)(xrow);
    float4 pb = *(const float4*)(xrow + 4);
    {
        short8 w;
        w[0]=f2bf(pa.x); w[1]=f2bf(pa.y); w[2]=f2bf(pa.z); w[3]=f2bf(pa.w);
        w[4]=f2bf(pb.x); w[5]=f2bf(pb.y); w[6]=f2bf(pb.z); w[7]=f2bf(pb.w);
        *(short8*)&Ab[0][achunk*8] = w;
    }

    for (int t = 0; t < 64; ++t) {
        const int cur = t & 1, nxt = cur ^ 1;
        __syncthreads();                      // buffer `cur` staging complete (full drain)
        const bool more = (t + 1) < 64;
        if (more) {
            // prefetch next B straight to LDS (DMA drains at NEXT barrier)
#pragma unroll
            for (int j = 0; j < 4; ++j)
                gl_lds16(WT + bsrc[j] + (t+1)*32, (void*)&Bb[nxt][bdst[j]]);
            // prefetch next A into registers (vmcnt wait deferred past compute)
            pa = *(const float4*)(xrow + (t+1)*32);
            pb = *(const float4*)(xrow + (t+1)*32 + 4);
        }
#pragma unroll
        for (int ks = 0; ks < 2; ++ks) {
            short8 a[2], bf[4];
#pragma unroll
            for (int mi = 0; mi < 2; ++mi)
                a[mi] = *(const short8*)&Ab[cur][ard[ks][mi]];
#pragma unroll
            for (int ni = 0; ni < 4; ++ni)
                bf[ni] = *(const short8*)&Bb[cur][brd[ks][ni]];
#pragma unroll
            for (int mi = 0; mi < 2; ++mi)
#pragma unroll
                for (int ni = 0; ni < 4; ++ni)
                    acc[mi][ni] = __builtin_amdgcn_mfma_f32_32x32x16_bf16(
                                      a[mi], bf[ni], acc[mi][ni], 0, 0, 0);
        }
        if (more) {
            // convert + write next A after compute (global latency hidden under MFMAs)
            short8 w;
            w[0]=f2bf(pa.x); w[1]=f2bf(pa.y); w[2]=f2bf(pa.z); w[3]=f2bf(pa.w);
            w[4]=f2bf(pb.x); w[5]=f2bf(pb.y); w[6]=f2bf(pb.z); w[7]=f2bf(pb.w);
            *(short8*)&Ab[nxt][achunk*8] = w;
        }
    }

    // ---- epilogue: relu(acc + att2c[b][n]) * Wfull[n], reduce over n, write att[m] ----
    // Bb[0]'s last read was step 62; every wave passed step-63's top barrier after that ->
    // safe to write epi (first 6KB of Bb[0]) without an extra barrier. Step-63 readers
    // touch only Ab[1]/Bb[1] (disjoint).
    float* epi = (float*)&Bb[0][0];  // [0..511]=Wfull, [512..1023]=att2c[b0], [1024..1535]=att2c[b1]
    const int b0i = m0 / L_;
    const int b1i = (m0 + 127) / L_;
    epi[tid]        = Wfull[tid];
    epi[512 + tid]  = att2c[(size_t)b0i*ATT_ + tid];
    epi[1024 + tid] = att2c[(size_t)b1i*ATT_ + tid];
    __syncthreads();
    const int split = (b0i + 1) * L_;   // first global row of batch b1
#pragma unroll
    for (int mi = 0; mi < 2; ++mi) {
#pragma unroll
        for (int reg = 0; reg < 16; ++reg) {
            int r32  = (reg & 3) + 8*(reg >> 2) + 4*laneh;   // verified C/D map (m74/m101)
            int mloc = wr*64 + mi*32 + r32;
            int off  = (m0 + mloc >= split) ? 1024 : 512;
            float v = 0.f;
#pragma unroll
            for (int ni = 0; ni < 4; ++ni) {
                int n = wc*128 + ni*32 + lane31;
                float tv = acc[mi][ni][reg] + epi[off + n];
                v = fmaf(fmaxf(tv, 0.f), epi[n], v);
            }
#pragma unroll
            for (int mask = 16; mask; mask >>= 1) v += __shfl_xor(v, mask, 64);
            if (lane31 == 0) att_ws[wc][mloc] = v;
        }
    }
    __syncthreads();
    if (tid < 128)
        att[m0 + tid] = att_ws[0][tid] + att_ws[1][tid] + att_ws[2][tid] + att_ws[3][tid];
}

// ---------- K2: softmax over L, z = alpha@x[b], out0 = gate*z, out1 = alpha ----------
// grid (B, 2): each block handles 1024 of 2048 ENC cols -> 512 blocks = 2/CU.
// Reversed block order + 7-deep float4 software pipeline (round-1 notes).
__global__ __launch_bounds__(256) void k_softz(
        const float* __restrict__ att, const float* __restrict__ x,
        const float* __restrict__ gate, float* __restrict__ out) {
    const int b = (B_ - 1) - (int)blockIdx.x;
    const int s = blockIdx.y, t = threadIdx.x;   // 256 threads
    __shared__ float sa[L_];
    __shared__ float red[8];
    const int wid = t >> 6, lane = t & 63;
    float v = (t < L_) ? att[b*L_ + t] : -1e30f;
    float m = v;
#pragma unroll
    for (int mask = 32; mask; mask >>= 1) m = fmaxf(m, __shfl_xor(m, mask, 64));
    if (lane == 0) red[wid] = m;
    __syncthreads();
    m = fmaxf(fmaxf(red[0], red[1]), fmaxf(red[2], red[3]));
    float e = (t < L_) ? __expf(v - m) : 0.f;
    float sum = e;
#pragma unroll
    for (int mask = 32; mask; mask >>= 1) sum += __shfl_xor(sum, mask, 64);
    if (lane == 0) red[4 + wid] = sum;
    __syncthreads();
    sum = red[4] + red[5] + red[6] + red[7];
    float alpha = e / sum;
    if (t < L_) {
        sa[t] = alpha;
        if (s == 0) out[(size_t)B_*ENC_ + (size_t)b*L_ + t] = alpha;
    }
    __syncthreads();
    const float* xb = x + (size_t)b*L_*ENC_ + s*1024 + t*4;
    float4 z = {0.f, 0.f, 0.f, 0.f};
    float4 u[7], w[7];
#pragma unroll
    for (int i = 0; i < 7; ++i) u[i] = *(const float4*)(xb + (size_t)i*ENC_);
    for (int l0 = 0; l0 < 183; l0 += 7) {          // consumes groups 0..182, prefetches 7..189
#pragma unroll
        for (int i = 0; i < 7; ++i)
            w[i] = *(const float4*)(xb + (size_t)(l0 + 7 + i)*ENC_);
#pragma unroll
        for (int i = 0; i < 7; ++i) {
            float a_ = sa[l0 + i];
            z.x = fmaf(a_, u[i].x, z.x); z.y = fmaf(a_, u[i].y, z.y);
            z.z = fmaf(a_, u[i].z, z.z); z.w = fmaf(a_, u[i].w, z.w);
        }
#pragma unroll
        for (int i = 0; i < 7; ++i) u[i] = w[i];
    }
#pragma unroll
    for (int i = 0; i < 7; ++i) {                  // final group l = 189..195
        float a_ = sa[189 + i];
        z.x = fmaf(a_, u[i].x, z.x); z.y = fmaf(a_, u[i].y, z.y);
        z.z = fmaf(a_, u[i].z, z.z); z.w = fmaf(a_, u[i].w, z.w);
    }
    const float gt = gate[b];
    float4 o; o.x = gt*z.x; o.y = gt*z.y; o.z = gt*z.z; o.w = gt*z.w;
    *(float4*)(out + (size_t)b*ENC_ + s*1024 + t*4) = o;
}

extern "C" void kernel_launch(void* const* d_in, const int* in_sizes, int n_in,
                              void* d_out, int out_size, void* d_ws, size_t ws_size,
                              hipStream_t stream) {
    const float* x      = (const float*)d_in[0];
    const float* h      = (const float*)d_in[1];
    const float* W_enc  = (const float*)d_in[2];
    const float* b_enc  = (const float*)d_in[3];
    const float* W_dec  = (const float*)d_in[4];
    const float* b_dec  = (const float*)d_in[5];
    const float* W_full = (const float*)d_in[6];
    // d_in[7] = b_full: softmax is shift-invariant -> unused
    const float* W_beta = (const float*)d_in[8];
    const float* b_beta = (const float*)d_in[9];
    float* out = (float*)d_out;

    char* ws = (char*)d_ws;
    unsigned short* WT = (unsigned short*)ws;                              // 2 MB
    float* att2c  = (float*)(ws + 2*1024*1024);                            // 512 KB
    float* gate   = (float*)(ws + 2*1024*1024 + 512*1024);                 // 1 KB
    float* attbuf = (float*)(ws + 2*1024*1024 + 512*1024 + 1024);          // 200 KB

    k_transpose<<<dim3(ENC_/32, ATT_/32), 256, 0, stream>>>(W_enc, WT);
    k_prep2   <<<B_/4, 256, 0, stream>>>(h, W_dec, b_dec, b_enc, W_beta, b_beta, att2c, gate);
    k_gemm    <<<M_TOT/128, 512, 0, stream>>>(x, WT, att2c, W_full, attbuf);
    k_softz   <<<dim3(B_, 2), 256, 0, stream>>>(attbuf, x, gate, out);
}